// Round 3
// baseline (38589.880 us; speedup 1.0000x reference)
//
#include <hip/hip_runtime.h>
#include <hip/hip_bf16.h>
#include <hip/hip_cooperative_groups.h>
#include <cstdint>
#include <cstddef>

namespace cg = cooperative_groups;

// Seq2Seq LSTM: 168 enc + 24 dec steps, 3 layers, B=512, H=1024, IN=64.
// Round 3: ONE persistent cooperative kernel (256 WGs = 1/CU), grid.sync()
// between cells — removes ~600 launch/drain overheads. Cell internals
// (packed bf16 hi/lo weights, global_load_lds, 3-buf counted vmcnt) unchanged.

typedef __attribute__((ext_vector_type(8))) short bf16x8;
typedef __attribute__((ext_vector_type(4))) float f32x4;
typedef __attribute__((address_space(3))) char lds_char;
typedef __attribute__((address_space(1))) char glb_char;

__device__ __forceinline__ void split1(float x, ushort &hi, ushort &lo) {
  unsigned u = __float_as_uint(x);
  hi = (ushort)(u >> 16);                         // truncated bf16 (exact)
  float r = x - __uint_as_float(u & 0xffff0000u); // exact remainder
  unsigned v = __float_as_uint(r);
  v += 0x7fffu + ((v >> 16) & 1u);                // RNE to bf16
  lo = (ushort)(v >> 16);
}
__device__ __forceinline__ ushort bf_part(float x, bool lo) {
  ushort h, l; split1(x, h, l); return lo ? l : h;
}

__device__ __forceinline__ void gload16(const char* g, char* l) {
  __builtin_amdgcn_global_load_lds((const __attribute__((address_space(1))) void*)(glb_char*)g,
                                   (__attribute__((address_space(3))) void*)(lds_char*)l,
                                   16, 0, 0);
}

// ---------------- pack kernels (run once per launch) -----------------------
// Weight block layout: [hb=64][kt=NT][16KB: 8KB hi | 8KB lo], each half the
// LDS image of a 64x64 bf16 tile with byte swizzle ((r&7)<<4) pre-applied.
__global__ void pack_w_kernel(const float* __restrict__ Wih,
                              const float* __restrict__ Whh,
                              ushort* __restrict__ dst, int K1, int NT,
                              long nchunk) {
  for (long c = blockIdx.x * (long)blockDim.x + threadIdx.x; c < nchunk;
       c += (long)gridDim.x * blockDim.x) {
    long p = c * 8;                       // byte position
    int blk = (int)(p >> 14);
    int off = (int)(p & 16383);
    int hb = blk / NT, kt = blk - hb * NT;
    bool lo = off >= 8192;
    int q = off & 8191;
    int r = q >> 7;
    int k = ((q & 127) ^ ((r & 7) << 4)) >> 1;   // 4 consecutive elems
    int j = (r >> 4) * 1024 + hb * 16 + (r & 15);
    int kcol = kt * 64 + k;
    float4 v;
    if (kcol < K1) v = *(const float4*)(Wih + (size_t)j * K1 + kcol);
    else           v = *(const float4*)(Whh + (size_t)j * 1024 + (kcol - K1));
    ushort4 o;
    o.x = bf_part(v.x, lo); o.y = bf_part(v.y, lo);
    o.z = bf_part(v.z, lo); o.w = bf_part(v.w, lo);
    *(ushort4*)(dst + (p >> 1)) = o;
  }
}

// x block layout: [t=168][mb=4][32KB: 16KB hi | 16KB lo], scale 1e-4 folded.
__global__ void pack_x_kernel(const float* __restrict__ x,
                              ushort* __restrict__ dst, long nchunk) {
  for (long c = blockIdx.x * (long)blockDim.x + threadIdx.x; c < nchunk;
       c += (long)gridDim.x * blockDim.x) {
    long p = c * 8;
    int blk = (int)(p >> 15);            // t*4 + mb
    int off = (int)(p & 32767);
    bool lo = off >= 16384;
    int q = off & 16383;
    int r = q >> 7;
    int k = ((q & 127) ^ ((r & 7) << 4)) >> 1;
    int t = blk >> 2, mb = blk & 3;
    float4 v = *(const float4*)(x + ((size_t)(t * 512 + mb * 128 + r) * 64 + k));
    ushort4 o;
    o.x = bf_part(v.x * 1e-4f, lo); o.y = bf_part(v.y * 1e-4f, lo);
    o.z = bf_part(v.z * 1e-4f, lo); o.w = bf_part(v.w * 1e-4f, lo);
    *(ushort4*)(dst + (p >> 1)) = o;
  }
}

// ---------------- one LSTM cell (device function) --------------------------
// LDS buffer = [Ah 16K|Al 16K|Bh 8K|Bl 8K] = 48K x 3 buffers; counted vmcnt.
// If outp != nullptr, also reduce out[row] += sum_j h[row,j]*Wout[j] (atomic).
__device__ void cell_dev(char* lds,
                         const char* A1p, const char* A2p, const char* Bp,
                         const float* bias, float* cst, char* hpk,
                         int NK1, float* outp, const float* Wout) {
  const int NT = NK1 + 16;
  const int tid = threadIdx.x;
  const int bw = blockIdx.x;
  const int wid = (bw & 7) * 32 + (bw >> 3);   // XCD swizzle
  const int mb = wid & 3, hb = wid >> 2;
  const int bm0 = mb * 128, hc0 = hb * 16;
  const int w = tid >> 6, lane = tid & 63;
  const int wm = w >> 1, wn = w & 1;           // wave 2x2 over 128x64
  const int l15 = lane & 15, l4 = lane >> 4;
  const int laneoff = lane * 16;

  f32x4 acc[4][2];
#pragma unroll
  for (int m = 0; m < 4; ++m)
#pragma unroll
    for (int n = 0; n < 2; ++n) acc[m][n] = (f32x4){0.f, 0.f, 0.f, 0.f};

  auto STAGE = [&](int buf, int kt) {
    const char* asrc;
    if (kt < NK1) asrc = A1p + (((size_t)(mb * NK1 + kt)) << 15);
    else          asrc = A2p + (((size_t)(mb * 16 + (kt - NK1))) << 15);
    const char* bsrc = Bp + (((size_t)(hb * NT + kt)) << 14);
    char* lb = lds + buf * 49152;
#pragma unroll
    for (int i = 0; i < 8; ++i) {
      int o = (i * 4 + w) * 1024;
      gload16(asrc + o + laneoff, lb + o);
    }
#pragma unroll
    for (int i = 0; i < 4; ++i) {
      int o = (i * 4 + w) * 1024;
      gload16(bsrc + o + laneoff, lb + 32768 + o);
    }
  };

  auto COMPUTE = [&](int buf) {
    const char* lb = lds + buf * 49152;
#pragma unroll
    for (int s = 0; s < 2; ++s) {
      bf16x8 ah[4], al[4], bh[2], bl[2];
#pragma unroll
      for (int m = 0; m < 4; ++m) {
        int row = wm * 64 + m * 16 + l15;
        int off = (row * 128 + s * 64 + l4 * 16) ^ ((l15 & 7) << 4);
        ah[m] = *(const bf16x8*)(lb + off);
        al[m] = *(const bf16x8*)(lb + 16384 + off);
      }
#pragma unroll
      for (int n = 0; n < 2; ++n) {
        int row = wn * 32 + n * 16 + l15;
        int off = (row * 128 + s * 64 + l4 * 16) ^ ((l15 & 7) << 4);
        bh[n] = *(const bf16x8*)(lb + 32768 + off);
        bl[n] = *(const bf16x8*)(lb + 40960 + off);
      }
#pragma unroll
      for (int m = 0; m < 4; ++m)
#pragma unroll
        for (int n = 0; n < 2; ++n) {
          acc[m][n] = __builtin_amdgcn_mfma_f32_16x16x32_bf16(ah[m], bh[n], acc[m][n], 0, 0, 0);
          acc[m][n] = __builtin_amdgcn_mfma_f32_16x16x32_bf16(ah[m], bl[n], acc[m][n], 0, 0, 0);
          acc[m][n] = __builtin_amdgcn_mfma_f32_16x16x32_bf16(al[m], bh[n], acc[m][n], 0, 0, 0);
        }
    }
  };

  STAGE(0, 0);
  STAGE(1, 1);
  int cb = 0;
  for (int kt = 0; kt < NT; ++kt) {
    if (kt + 2 < NT) {
      int sb = cb + 2; if (sb >= 3) sb -= 3;
      STAGE(sb, kt + 2);
      __builtin_amdgcn_sched_barrier(0);
      asm volatile("s_waitcnt vmcnt(24)" ::: "memory");   // tile kt landed
    } else if (kt + 1 < NT) {
      __builtin_amdgcn_sched_barrier(0);
      asm volatile("s_waitcnt vmcnt(12)" ::: "memory");
    } else {
      __builtin_amdgcn_sched_barrier(0);
      asm volatile("s_waitcnt vmcnt(0)" ::: "memory");
    }
    __builtin_amdgcn_s_barrier();
    __builtin_amdgcn_sched_barrier(0);
    asm volatile("" ::: "memory");
    COMPUTE(cb);
    __builtin_amdgcn_sched_barrier(0);
    __builtin_amdgcn_s_barrier();   // protect buffer overwrite next iter
    __builtin_amdgcn_sched_barrier(0);
    if (++cb == 3) cb = 0;
  }

  // Epilogue: z -> LDS (C/D layout col=lane&15, row=(lane>>4)*4+reg), gates.
  float* z = (float*)lds;
#pragma unroll
  for (int m = 0; m < 4; ++m)
#pragma unroll
    for (int n = 0; n < 2; ++n)
#pragma unroll
      for (int j = 0; j < 4; ++j) {
        int row = wm * 64 + m * 16 + l4 * 4 + j;
        int col = wn * 32 + n * 16 + l15;
        z[row * 68 + col] = acc[m][n][j];
      }
  __syncthreads();
#pragma unroll
  for (int i = 0; i < 8; ++i) {
    int idx = i * 256 + tid;
    int b = idx >> 4, hc = idx & 15;
    int jj = hc0 + hc;
    float zi = z[b * 68 + hc]      + bias[jj];
    float zf = z[b * 68 + 16 + hc] + bias[1024 + jj];
    float zg = z[b * 68 + 32 + hc] + bias[2048 + jj];
    float zo = z[b * 68 + 48 + hc] + bias[3072 + jj];
    size_t gi = (size_t)(bm0 + b) * 1024 + jj;
    float cp = cst[gi];
    float si = 1.f / (1.f + expf(-zi));
    float sf = 1.f / (1.f + expf(-zf));
    float so = 1.f / (1.f + expf(-zo));
    float cn = sf * cp + si * tanhf(zg);
    float hn = so * tanhf(cn);
    cst[gi] = cn;
    // packed hi/lo write in A-tile image layout for downstream cells
    ushort hhi, hlo; split1(hn, hhi, hlo);
    int r = b;
    int kt2 = jj >> 6, k2 = jj & 63;
    size_t blk = ((size_t)(mb * 16 + kt2)) << 15;
    int inner = (k2 * 2) ^ ((r & 7) << 4);
    *(ushort*)(hpk + blk + r * 128 + inner) = hhi;
    *(ushort*)(hpk + blk + 16384 + r * 128 + inner) = hlo;
    if (outp) {   // fused projection: 16-lane reduce over this WG's 16 cols
      float contrib = hn * Wout[jj];
      contrib += __shfl_xor(contrib, 1, 64);
      contrib += __shfl_xor(contrib, 2, 64);
      contrib += __shfl_xor(contrib, 4, 64);
      contrib += __shfl_xor(contrib, 8, 64);
      if ((lane & 15) == 0) atomicAdd(outp + bm0 + b, contrib);
    }
  }
  __syncthreads();  // z reads done before next cell's STAGE overwrites lds
}

// ---------------- persistent cooperative kernel ----------------------------
struct SeqParams {
  const char* xp;
  const char* wp0; const char* wp1; const char* wp2;
  const char* wp3; const char* wp4; const char* wp5;
  const float* b0; const float* b1; const float* b2;
  const float* b3; const float* b4; const float* b5;
  float* c0; float* c1; float* c2;
  char* h0a; char* h0b; char* h1a; char* h1b; char* h2a; char* h2b;
  char* yp; const float* Wout; float* out;
};

__global__ __launch_bounds__(256, 1) void seq_kernel(SeqParams P) {
  cg::grid_group grid = cg::this_grid();
  __shared__ __align__(16) char lds[3 * 49152];
  char* h0[2] = { P.h0a, P.h0b };
  char* h1[2] = { P.h1a, P.h1b };
  char* h2[2] = { P.h2a, P.h2b };
  int p0 = 0, p1 = 0, p2 = 0;

  for (int t = 0; t < 168; ++t) {
    cell_dev(lds, P.xp + (size_t)t * 131072, h0[p0], P.wp0, P.b0, P.c0,
             h0[p0 ^ 1], 1, nullptr, nullptr);
    p0 ^= 1; grid.sync();
    cell_dev(lds, h0[p0], h1[p1], P.wp1, P.b1, P.c1, h1[p1 ^ 1], 16, nullptr, nullptr);
    p1 ^= 1; grid.sync();
    cell_dev(lds, h1[p1], h2[p2], P.wp2, P.b2, P.c2, h2[p2 ^ 1], 16, nullptr, nullptr);
    p2 ^= 1; grid.sync();
  }

  // snapshot y = enc-final h2: each WG copies ONLY the bytes it wrote itself
  {
    const int tid = threadIdx.x;
    const int bw = blockIdx.x;
    const int wid = (bw & 7) * 32 + (bw >> 3);
    const int mb = wid & 3, hb = wid >> 2;
    const int hc0 = hb * 16;
    const char* src = h2[p2];
#pragma unroll
    for (int i = 0; i < 8; ++i) {
      int idx = i * 256 + tid;
      int b = idx >> 4, hc = idx & 15;
      int jj = hc0 + hc;
      int kt2 = jj >> 6, k2 = jj & 63;
      size_t blk = ((size_t)(mb * 16 + kt2)) << 15;
      size_t o1 = blk + (size_t)b * 128 + ((k2 * 2) ^ ((b & 7) << 4));
      *(ushort*)(P.yp + o1) = *(const ushort*)(src + o1);
      *(ushort*)(P.yp + o1 + 16384) = *(const ushort*)(src + o1 + 16384);
    }
  }
  grid.sync();

  for (int t = 0; t < 24; ++t) {
    cell_dev(lds, P.yp, h0[p0], P.wp3, P.b3, P.c0, h0[p0 ^ 1], 16, nullptr, nullptr);
    p0 ^= 1; grid.sync();
    cell_dev(lds, h0[p0], h1[p1], P.wp4, P.b4, P.c1, h1[p1 ^ 1], 16, nullptr, nullptr);
    p1 ^= 1; grid.sync();
    cell_dev(lds, h1[p1], h2[p2], P.wp5, P.b5, P.c2, h2[p2 ^ 1], 16,
             P.out + t * 512, P.Wout);
    p2 ^= 1; grid.sync();
  }
}

// fallback wrapper: one cell per launch (used only if cooperative launch fails)
__global__ __launch_bounds__(256, 1) void lstm_cell_one(
    const char* A1p, const char* A2p, const char* Bp, const float* bias,
    float* cst, char* hpk, int NK1, float* outp, const float* Wout) {
  __shared__ __align__(16) char lds[3 * 49152];
  cell_dev(lds, A1p, A2p, Bp, bias, cst, hpk, NK1, outp, Wout);
}

extern "C" void kernel_launch(void* const* d_in, const int* in_sizes, int n_in,
                              void* d_out, int out_size, void* d_ws, size_t ws_size,
                              hipStream_t stream) {
  (void)in_sizes; (void)n_in; (void)ws_size;
  const float* x = (const float*)d_in[0];
  const float* Wih[6]; const float* Whh[6]; const float* bb[6];
  for (int i = 0; i < 6; ++i) {
    Wih[i] = (const float*)d_in[1 + 3 * i];
    Whh[i] = (const float*)d_in[2 + 3 * i];
    bb[i]  = (const float*)d_in[3 + 3 * i];
  }
  const float* Wout = (const float*)d_in[19];
  float* out = (float*)d_out;

  char* W = (char*)d_ws;
  const size_t MB2 = 2097152;
  float* c0 = (float*)(W + 0 * MB2);
  float* c1 = (float*)(W + 1 * MB2);
  float* c2 = (float*)(W + 2 * MB2);
  char* h0p[2] = { W + 3 * MB2, W + 4 * MB2 };
  char* h1p[2] = { W + 5 * MB2, W + 6 * MB2 };
  char* h2p[2] = { W + 7 * MB2, W + 8 * MB2 };
  char* yp = W + 9 * MB2;
  char* xp = W + 11 * MB2;
  char* wp[6];
  wp[0] = xp + 22020096;
  wp[1] = wp[0] + 17825792;
  for (int i = 2; i < 6; ++i) wp[i] = wp[i - 1] + 33554432;

  hipMemsetAsync(W, 0, 9 * MB2, stream);                    // c + h state
  hipMemsetAsync(d_out, 0, (size_t)out_size * sizeof(float), stream);

  pack_w_kernel<<<dim3(1024), dim3(256), 0, stream>>>(
      Wih[0], Whh[0], (ushort*)wp[0], 64, 17, 64L * 17 * 2048);
  for (int i = 1; i < 6; ++i)
    pack_w_kernel<<<dim3(1024), dim3(256), 0, stream>>>(
        Wih[i], Whh[i], (ushort*)wp[i], 1024, 32, 64L * 32 * 2048);
  pack_x_kernel<<<dim3(1024), dim3(256), 0, stream>>>(
      x, (ushort*)xp, 22020096L / 8);

  SeqParams P;
  P.xp = xp;
  P.wp0 = wp[0]; P.wp1 = wp[1]; P.wp2 = wp[2];
  P.wp3 = wp[3]; P.wp4 = wp[4]; P.wp5 = wp[5];
  P.b0 = bb[0]; P.b1 = bb[1]; P.b2 = bb[2];
  P.b3 = bb[3]; P.b4 = bb[4]; P.b5 = bb[5];
  P.c0 = c0; P.c1 = c1; P.c2 = c2;
  P.h0a = h0p[0]; P.h0b = h0p[1];
  P.h1a = h1p[0]; P.h1b = h1p[1];
  P.h2a = h2p[0]; P.h2b = h2p[1];
  P.yp = yp; P.Wout = Wout; P.out = out;
  void* args[] = { &P };

  hipError_t e = hipLaunchCooperativeKernel((void*)seq_kernel, dim3(256),
                                            dim3(256), args, 0, stream);
  if (e != hipSuccess) {
    // fallback: per-cell launches (round-2 structure, proj fused via atomics)
    dim3 grid(256), block(256);
    int p0 = 0, p1 = 0, p2 = 0;
    for (int t = 0; t < 168; ++t) {
      lstm_cell_one<<<grid, block, 0, stream>>>(
          xp + (size_t)t * 131072, h0p[p0], wp[0], bb[0], c0, h0p[p0 ^ 1], 1,
          nullptr, nullptr);
      p0 ^= 1;
      lstm_cell_one<<<grid, block, 0, stream>>>(
          h0p[p0], h1p[p1], wp[1], bb[1], c1, h1p[p1 ^ 1], 16, nullptr, nullptr);
      p1 ^= 1;
      lstm_cell_one<<<grid, block, 0, stream>>>(
          h1p[p1], h2p[p2], wp[2], bb[2], c2, h2p[p2 ^ 1], 16, nullptr, nullptr);
      p2 ^= 1;
    }
    hipMemcpyAsync(yp, h2p[p2], MB2, hipMemcpyDeviceToDevice, stream);
    for (int t = 0; t < 24; ++t) {
      lstm_cell_one<<<grid, block, 0, stream>>>(
          yp, h0p[p0], wp[3], bb[3], c0, h0p[p0 ^ 1], 16, nullptr, nullptr);
      p0 ^= 1;
      lstm_cell_one<<<grid, block, 0, stream>>>(
          h0p[p0], h1p[p1], wp[4], bb[4], c1, h1p[p1 ^ 1], 16, nullptr, nullptr);
      p1 ^= 1;
      lstm_cell_one<<<grid, block, 0, stream>>>(
          h1p[p1], h2p[p2], wp[5], bb[5], c2, h2p[p2 ^ 1], 16,
          out + (size_t)t * 512, Wout);
      p2 ^= 1;
    }
  }
}

// Round 4
// 18997.667 us; speedup vs baseline: 2.0313x; 2.0313x over previous
//
#include <hip/hip_runtime.h>
#include <hip/hip_bf16.h>
#include <cstdint>
#include <cstddef>

// Seq2Seq LSTM: 168 enc + 24 dec steps, 3 layers, B=512, H=1024, IN=64.
// Round 4: back to per-cell launches (CG grid.sync measured ~32us -> removed).
// A-operand (h/x/y) kept in GLOBAL pre-packed MFMA-fragment layout, loaded
// straight to VGPRs (depth-1 dbuf). Only B (weights) goes through LDS
// (3 bufs, counted vmcnt). 1x4 wave layout => lane-local gates epilogue,
// no z-LDS roundtrip; decoder projection fused via shfl+atomicAdd.

typedef __attribute__((ext_vector_type(8))) short bf16x8;
typedef __attribute__((ext_vector_type(4))) float f32x4;
typedef __attribute__((address_space(3))) char lds_char;
typedef __attribute__((address_space(1))) char glb_char;

__device__ __forceinline__ void split1(float x, ushort &hi, ushort &lo) {
  unsigned u = __float_as_uint(x);
  hi = (ushort)(u >> 16);                         // truncated bf16 (exact)
  float r = x - __uint_as_float(u & 0xffff0000u); // exact remainder
  unsigned v = __float_as_uint(r);
  v += 0x7fffu + ((v >> 16) & 1u);                // RNE to bf16
  lo = (ushort)(v >> 16);
}
__device__ __forceinline__ ushort bf_part(float x, bool lo) {
  ushort h, l; split1(x, h, l); return lo ? l : h;
}

__device__ __forceinline__ void gload16(const char* g, char* l) {
  __builtin_amdgcn_global_load_lds((const __attribute__((address_space(1))) void*)(glb_char*)g,
                                   (__attribute__((address_space(3))) void*)(lds_char*)l,
                                   16, 0, 0);
}

// ---------------- pack kernels (once per launch) ---------------------------
// B (weights): [hb=64][kt=NT][16KB: 8KB hi | 8KB lo]; r = col index (n*16+l15
// order), byte (r*128 + k*2) ^ ((r&7)<<4) within half. UNCHANGED from r2/r3.
__global__ void pack_w_kernel(const float* __restrict__ Wih,
                              const float* __restrict__ Whh,
                              ushort* __restrict__ dst, int K1, int NT,
                              long nchunk) {
  for (long c = blockIdx.x * (long)blockDim.x + threadIdx.x; c < nchunk;
       c += (long)gridDim.x * blockDim.x) {
    long p = c * 8;                       // byte position
    int blk = (int)(p >> 14);
    int off = (int)(p & 16383);
    int hb = blk / NT, kt = blk - hb * NT;
    bool lo = off >= 8192;
    int q = off & 8191;
    int r = q >> 7;
    int k = ((q & 127) ^ ((r & 7) << 4)) >> 1;   // 4 consecutive elems
    int j = (r >> 4) * 1024 + hb * 16 + (r & 15);
    int kcol = kt * 64 + k;
    float4 v;
    if (kcol < K1) v = *(const float4*)(Wih + (size_t)j * K1 + kcol);
    else           v = *(const float4*)(Whh + (size_t)j * 1024 + (kcol - K1));
    ushort4 o;
    o.x = bf_part(v.x, lo); o.y = bf_part(v.y, lo);
    o.z = bf_part(v.z, lo); o.w = bf_part(v.w, lo);
    *(ushort4*)(dst + (p >> 1)) = o;
  }
}

// A-fragment image: per (mb, kt) a 32KB block of 32 instr-slots
// slot j = mm*4 + s*2 + h (mm=0..7 row-16-blocks, s=k32-phase, h=hi/lo);
// within slot, lane l (64) * 16B: elems = A[mm*16+(l&15)][kt*64+s*32+(l>>4)*8+e]
// x: blocks ordered [t][mb], 1 kt each, scale 1e-4 folded in.
__global__ void pack_x_frag(const float* __restrict__ x, char* __restrict__ dst,
                            long n16) {
  for (long c = blockIdx.x * (long)blockDim.x + threadIdx.x; c < n16;
       c += (long)gridDim.x * blockDim.x) {
    long p = c * 16;
    int blk = (int)(p >> 15);
    int inside = (int)(p & 32767);
    int idx16 = inside >> 4;
    int j = idx16 >> 6, lane = idx16 & 63;
    int mm = j >> 2, s = (j >> 1) & 1, h = j & 1;
    int t = blk >> 2, mb = blk & 3;
    int row = mm * 16 + (lane & 15);
    int k = s * 32 + (lane >> 4) * 8;
    const float* src = x + ((size_t)(t * 512 + mb * 128 + row) * 64 + k);
    ushort o[8];
#pragma unroll
    for (int e = 0; e < 8; ++e) o[e] = bf_part(src[e] * 1e-4f, h);
    *(ushort4*)(dst + p) = make_ushort4(o[0], o[1], o[2], o[3]);
    *(ushort4*)(dst + p + 8) = make_ushort4(o[4], o[5], o[6], o[7]);
  }
}

// ---------------- main cell kernel -----------------------------------------
// grid 256 WGs = 4 mb x 64 hb; 4 waves stacked (wave w = rows w*32..+31).
// NK1: #64-k tiles of the first A operand (1 for x, 16 for h/y).
template <int NK1>
__global__ __launch_bounds__(256, 1) void lstm_cell(
    const char* __restrict__ A1p, const char* __restrict__ A2p,
    const char* __restrict__ Bp, const float* __restrict__ bias,
    float* __restrict__ cst, char* __restrict__ hpk,
    float* __restrict__ outp, const float* __restrict__ Wout) {
  constexpr int NT = NK1 + 16;
  __shared__ __align__(16) char lds[3 * 16384];

  const int tid = threadIdx.x;
  const int bw = blockIdx.x;
  const int wid = (bw & 7) * 32 + (bw >> 3);   // XCD swizzle
  const int mb = wid & 3, hb = wid >> 2;
  const int bm0 = mb * 128, hc0 = hb * 16;
  const int w = tid >> 6, lane = tid & 63;
  const int l15 = lane & 15, l4 = lane >> 4;

  f32x4 acc[2][4];
#pragma unroll
  for (int m = 0; m < 2; ++m)
#pragma unroll
    for (int n = 0; n < 4; ++n) acc[m][n] = (f32x4){0.f, 0.f, 0.f, 0.f};

  bf16x8 a0[8], a1[8];

  auto ALOAD = [&](bf16x8(&a)[8], int kt) {
    const char* ab = (kt < NK1)
        ? A1p + (((size_t)(mb * NK1 + kt)) << 15)
        : A2p + (((size_t)(mb * 16 + (kt - NK1))) << 15);
    ab += (size_t)w * 8192 + (size_t)lane * 16;
#pragma unroll
    for (int j = 0; j < 8; ++j) a[j] = *(const bf16x8*)(ab + j * 1024);
  };

  auto BSTAGE = [&](int buf, int kt) {
    const char* bsrc = Bp + (((size_t)(hb * NT + kt)) << 14) + (size_t)lane * 16;
    char* lb = lds + buf * 16384;
#pragma unroll
    for (int i = 0; i < 4; ++i) {
      int o = (i * 4 + w) * 1024;
      gload16(bsrc + o, lb + o);
    }
  };

  auto COMPUTE = [&](int buf, bf16x8(&a)[8]) {
    const char* lb = lds + buf * 16384;
#pragma unroll
    for (int s = 0; s < 2; ++s) {
      bf16x8 bh[4], bl[4];
#pragma unroll
      for (int n = 0; n < 4; ++n) {
        int off = (((n * 16 + l15) * 128) + s * 64 + l4 * 16) ^ ((l15 & 7) << 4);
        bh[n] = *(const bf16x8*)(lb + off);
        bl[n] = *(const bf16x8*)(lb + 8192 + off);
      }
#pragma unroll
      for (int m = 0; m < 2; ++m) {
        bf16x8 aH = a[m * 4 + s * 2];
        bf16x8 aL = a[m * 4 + s * 2 + 1];
#pragma unroll
        for (int n = 0; n < 4; ++n) {
          acc[m][n] = __builtin_amdgcn_mfma_f32_16x16x32_bf16(aH, bh[n], acc[m][n], 0, 0, 0);
          acc[m][n] = __builtin_amdgcn_mfma_f32_16x16x32_bf16(aH, bl[n], acc[m][n], 0, 0, 0);
          acc[m][n] = __builtin_amdgcn_mfma_f32_16x16x32_bf16(aL, bh[n], acc[m][n], 0, 0, 0);
        }
      }
    }
  };

  int cb = 0;
  auto ITER = [&](bf16x8(&aC)[8], bf16x8(&aN)[8], int kt) {
    if (kt + 1 < NT) ALOAD(aN, kt + 1);
    if (kt + 2 < NT) {
      int sb = cb + 2; if (sb >= 3) sb -= 3;
      BSTAGE(sb, kt + 2);
    }
    __builtin_amdgcn_sched_barrier(0);
    if (kt + 2 < NT)      asm volatile("s_waitcnt vmcnt(16)" ::: "memory");
    else if (kt + 1 < NT) asm volatile("s_waitcnt vmcnt(12)" ::: "memory");
    else                  asm volatile("s_waitcnt vmcnt(0)" ::: "memory");
    __builtin_amdgcn_s_barrier();
    __builtin_amdgcn_sched_barrier(0);
    COMPUTE(cb, aC);
    __builtin_amdgcn_sched_barrier(0);
    __builtin_amdgcn_s_barrier();   // protect staged buffer for next iter
    __builtin_amdgcn_sched_barrier(0);
    if (++cb == 3) cb = 0;
  };

  ALOAD(a0, 0);
  BSTAGE(0, 0);
  BSTAGE(1, 1);
  for (int kt = 0; kt + 1 < NT; kt += 2) { ITER(a0, a1, kt); ITER(a1, a0, kt + 1); }
  if (NT & 1) ITER(a0, a1, NT - 1);

  // ---- lane-local epilogue: acc[m][n][j] = z[w*32+m*16+l4*4+j][gate n, col l15]
  const int jj = hc0 + l15;
  const float bi = bias[jj], bf_ = bias[1024 + jj];
  const float bg = bias[2048 + jj], bo = bias[3072 + jj];
  // h-fragment write precompute (consumer A layout)
  const int kk = jj & 63;
  const int s2 = (kk >> 5) & 1, c4 = (kk >> 3) & 3, e2 = kk & 7;
  char* hbase = hpk + (((size_t)(mb * 16 + (jj >> 6))) << 15) + e2 * 2;
#pragma unroll
  for (int m = 0; m < 2; ++m)
#pragma unroll
    for (int j = 0; j < 4; ++j) {
      const int r = w * 32 + m * 16 + l4 * 4 + j;   // row within 128-block
      const size_t gi = (size_t)(bm0 + r) * 1024 + jj;
      float zi = acc[m][0][j] + bi;
      float zf = acc[m][1][j] + bf_;
      float zg = acc[m][2][j] + bg;
      float zo = acc[m][3][j] + bo;
      float cp = cst[gi];
      float si = 1.f / (1.f + expf(-zi));
      float sf = 1.f / (1.f + expf(-zf));
      float so = 1.f / (1.f + expf(-zo));
      float cn = sf * cp + si * tanhf(zg);
      float hn = so * tanhf(cn);
      cst[gi] = cn;
      ushort hhi, hlo; split1(hn, hhi, hlo);
      const int mm = r >> 4;
      const int lane2 = (r & 15) | (c4 << 4);
      char* hb2 = hbase + ((mm * 4 + s2 * 2) * 64 + lane2) * 16;
      *(ushort*)hb2 = hhi;
      *(ushort*)(hb2 + 1024) = hlo;                 // h=1 slot (+64*16)
      if (outp) {                                    // fused projection
        float contrib = hn * Wout[jj];
        contrib += __shfl_xor(contrib, 1, 64);
        contrib += __shfl_xor(contrib, 2, 64);
        contrib += __shfl_xor(contrib, 4, 64);
        contrib += __shfl_xor(contrib, 8, 64);
        if (l15 == 0) atomicAdd(outp + bm0 + r, contrib);
      }
    }
}

extern "C" void kernel_launch(void* const* d_in, const int* in_sizes, int n_in,
                              void* d_out, int out_size, void* d_ws, size_t ws_size,
                              hipStream_t stream) {
  (void)in_sizes; (void)n_in; (void)ws_size;
  const float* x = (const float*)d_in[0];
  const float* Wih[6]; const float* Whh[6]; const float* bb[6];
  for (int i = 0; i < 6; ++i) {
    Wih[i] = (const float*)d_in[1 + 3 * i];
    Whh[i] = (const float*)d_in[2 + 3 * i];
    bb[i]  = (const float*)d_in[3 + 3 * i];
  }
  const float* Wout = (const float*)d_in[19];
  float* out = (float*)d_out;

  char* W = (char*)d_ws;
  const size_t MB2 = 2097152;
  float* c0 = (float*)(W + 0 * MB2);
  float* c1 = (float*)(W + 1 * MB2);
  float* c2 = (float*)(W + 2 * MB2);
  char* h0p[2] = { W + 3 * MB2, W + 4 * MB2 };
  char* h1p[2] = { W + 5 * MB2, W + 6 * MB2 };
  char* h2p[2] = { W + 7 * MB2, W + 8 * MB2 };
  char* yp = W + 9 * MB2;
  char* xp = W + 10 * MB2;                  // 168*4*32KB = 22,020,096 B
  char* wp[6];
  wp[0] = xp + 22020096;                    // 17*64*16KB = 17,825,792 B
  wp[1] = wp[0] + 17825792;                 // 32*64*16KB = 33,554,432 B each
  for (int i = 2; i < 6; ++i) wp[i] = wp[i - 1] + 33554432;

  hipMemsetAsync(W, 0, 9 * MB2, stream);                     // c + h state
  hipMemsetAsync(d_out, 0, (size_t)out_size * sizeof(float), stream);

  pack_w_kernel<<<dim3(1024), dim3(256), 0, stream>>>(
      Wih[0], Whh[0], (ushort*)wp[0], 64, 17, 64L * 17 * 2048);
  for (int i = 1; i < 6; ++i)
    pack_w_kernel<<<dim3(1024), dim3(256), 0, stream>>>(
        Wih[i], Whh[i], (ushort*)wp[i], 1024, 32, 64L * 32 * 2048);
  pack_x_frag<<<dim3(1024), dim3(256), 0, stream>>>(x, xp, 22020096L / 16);

  dim3 grid(256), block(256);
  int p0 = 0, p1 = 0, p2 = 0;
  for (int t = 0; t < 168; ++t) {
    lstm_cell<1><<<grid, block, 0, stream>>>(
        xp + (size_t)t * 131072, h0p[p0], wp[0], bb[0], c0, h0p[p0 ^ 1],
        nullptr, nullptr);
    p0 ^= 1;
    lstm_cell<16><<<grid, block, 0, stream>>>(
        h0p[p0], h1p[p1], wp[1], bb[1], c1, h1p[p1 ^ 1], nullptr, nullptr);
    p1 ^= 1;
    lstm_cell<16><<<grid, block, 0, stream>>>(
        h1p[p1], h2p[p2], wp[2], bb[2], c2, h2p[p2 ^ 1], nullptr, nullptr);
    p2 ^= 1;
  }
  hipMemcpyAsync(yp, h2p[p2], MB2, hipMemcpyDeviceToDevice, stream);
  for (int t = 0; t < 24; ++t) {
    lstm_cell<16><<<grid, block, 0, stream>>>(
        yp, h0p[p0], wp[3], bb[3], c0, h0p[p0 ^ 1], nullptr, nullptr);
    p0 ^= 1;
    lstm_cell<16><<<grid, block, 0, stream>>>(
        h0p[p0], h1p[p1], wp[4], bb[4], c1, h1p[p1 ^ 1], nullptr, nullptr);
    p1 ^= 1;
    lstm_cell<16><<<grid, block, 0, stream>>>(
        h1p[p1], h2p[p2], wp[5], bb[5], c2, h2p[p2 ^ 1],
        out + (size_t)t * 512, Wout);
    p2 ^= 1;
  }
}

// Round 5
// 11427.183 us; speedup vs baseline: 3.3770x; 1.6625x over previous
//
#include <hip/hip_runtime.h>
#include <hip/hip_bf16.h>
#include <cstdint>
#include <cstddef>

// Seq2Seq LSTM: 168 enc + 24 dec steps, 3 layers, B=512, H=1024, IN=64.
// Round 5: diagonal-wavefront fusion — cells (t,L0),(t-1,L1),(t-2,L2) are
// independent, so one launch runs all three: 768 WGs = 3 WGs/CU (12 waves/CU)
// for latency hiding; 196 launches instead of 600. Cell internals from r4:
// A (h/x/y) pre-packed MFMA-fragment image -> VGPR direct (depth-1 dbuf);
// B (weights) pre-packed swizzled LDS image -> global_load_lds, 3 bufs,
// counted vmcnt. Lane-local gate epilogue; projection fused via atomics.

typedef __attribute__((ext_vector_type(8))) short bf16x8;
typedef __attribute__((ext_vector_type(4))) float f32x4;
typedef __attribute__((address_space(3))) char lds_char;
typedef __attribute__((address_space(1))) char glb_char;

__device__ __forceinline__ void split1(float x, ushort &hi, ushort &lo) {
  unsigned u = __float_as_uint(x);
  hi = (ushort)(u >> 16);                         // truncated bf16 (exact)
  float r = x - __uint_as_float(u & 0xffff0000u); // exact remainder
  unsigned v = __float_as_uint(r);
  v += 0x7fffu + ((v >> 16) & 1u);                // RNE to bf16
  lo = (ushort)(v >> 16);
}
__device__ __forceinline__ ushort bf_part(float x, bool lo) {
  ushort h, l; split1(x, h, l); return lo ? l : h;
}

__device__ __forceinline__ void gload16(const char* g, char* l) {
  __builtin_amdgcn_global_load_lds((const __attribute__((address_space(1))) void*)(glb_char*)g,
                                   (__attribute__((address_space(3))) void*)(lds_char*)l,
                                   16, 0, 0);
}

// ---------------- pack kernels (once per launch) ---------------------------
// B (weights): [hb=64][kt=NT][16KB: 8KB hi | 8KB lo]; byte
// (r*128 + k*2) ^ ((r&7)<<4) within half, r = z-col fragment row.
__global__ void pack_w_kernel(const float* __restrict__ Wih,
                              const float* __restrict__ Whh,
                              ushort* __restrict__ dst, int K1, int NT,
                              long nchunk) {
  for (long c = blockIdx.x * (long)blockDim.x + threadIdx.x; c < nchunk;
       c += (long)gridDim.x * blockDim.x) {
    long p = c * 8;                       // byte position
    int blk = (int)(p >> 14);
    int off = (int)(p & 16383);
    int hb = blk / NT, kt = blk - hb * NT;
    bool lo = off >= 8192;
    int q = off & 8191;
    int r = q >> 7;
    int k = ((q & 127) ^ ((r & 7) << 4)) >> 1;   // 4 consecutive elems
    int j = (r >> 4) * 1024 + hb * 16 + (r & 15);
    int kcol = kt * 64 + k;
    float4 v;
    if (kcol < K1) v = *(const float4*)(Wih + (size_t)j * K1 + kcol);
    else           v = *(const float4*)(Whh + (size_t)j * 1024 + (kcol - K1));
    ushort4 o;
    o.x = bf_part(v.x, lo); o.y = bf_part(v.y, lo);
    o.z = bf_part(v.z, lo); o.w = bf_part(v.w, lo);
    *(ushort4*)(dst + (p >> 1)) = o;
  }
}

// A-fragment image: per (mb, kt) a 32KB block of 32 instr-slots
// slot j = mm*4 + s*2 + h; within slot lane l*16B:
// elems = A[mm*16+(l&15)][kt*64+s*32+(l>>4)*8+e]. x: [t][mb], 1e-4 folded.
__global__ void pack_x_frag(const float* __restrict__ x, char* __restrict__ dst,
                            long n16) {
  for (long c = blockIdx.x * (long)blockDim.x + threadIdx.x; c < n16;
       c += (long)gridDim.x * blockDim.x) {
    long p = c * 16;
    int blk = (int)(p >> 15);
    int inside = (int)(p & 32767);
    int idx16 = inside >> 4;
    int j = idx16 >> 6, lane = idx16 & 63;
    int mm = j >> 2, s = (j >> 1) & 1, h = j & 1;
    int t = blk >> 2, mb = blk & 3;
    int row = mm * 16 + (lane & 15);
    int k = s * 32 + (lane >> 4) * 8;
    const float* src = x + ((size_t)(t * 512 + mb * 128 + row) * 64 + k);
    ushort o[8];
#pragma unroll
    for (int e = 0; e < 8; ++e) o[e] = bf_part(src[e] * 1e-4f, h);
    *(ushort4*)(dst + p) = make_ushort4(o[0], o[1], o[2], o[3]);
    *(ushort4*)(dst + p + 8) = make_ushort4(o[4], o[5], o[6], o[7]);
  }
}

// ---------------- one LSTM cell (device function) --------------------------
struct CellA {
  const char* A1; const char* A2; const char* B;
  const float* bias; float* cst; char* hpk;
  float* outp; const float* Wout;
};
struct TriP { CellA c[3]; unsigned active; };

template <int NK1>
__device__ void cell_dev(char* lds, int ib, const CellA& C) {
  constexpr int NT = NK1 + 16;
  const int tid = threadIdx.x;
  const int wid = (ib & 7) * 32 + (ib >> 3);   // XCD swizzle (per 256 block)
  const int mb = wid & 3, hb = wid >> 2;
  const int bm0 = mb * 128, hc0 = hb * 16;
  const int w = tid >> 6, lane = tid & 63;
  const int l15 = lane & 15, l4 = lane >> 4;

  f32x4 acc[2][4];
#pragma unroll
  for (int m = 0; m < 2; ++m)
#pragma unroll
    for (int n = 0; n < 4; ++n) acc[m][n] = (f32x4){0.f, 0.f, 0.f, 0.f};

  bf16x8 a0[8], a1[8];

  auto ALOAD = [&](bf16x8(&a)[8], int kt) {
    const char* ab = (kt < NK1)
        ? C.A1 + (((size_t)(mb * NK1 + kt)) << 15)
        : C.A2 + (((size_t)(mb * 16 + (kt - NK1))) << 15);
    ab += (size_t)w * 8192 + (size_t)lane * 16;
#pragma unroll
    for (int j = 0; j < 8; ++j) a[j] = *(const bf16x8*)(ab + j * 1024);
  };

  auto BSTAGE = [&](int buf, int kt) {
    const char* bsrc = C.B + (((size_t)(hb * NT + kt)) << 14) + (size_t)lane * 16;
    char* lb = lds + buf * 16384;
#pragma unroll
    for (int i = 0; i < 4; ++i) {
      int o = (i * 4 + w) * 1024;
      gload16(bsrc + o, lb + o);
    }
  };

  auto COMPUTE = [&](int buf, bf16x8(&a)[8]) {
    const char* lb = lds + buf * 16384;
#pragma unroll
    for (int s = 0; s < 2; ++s) {
      bf16x8 bh[4], bl[4];
#pragma unroll
      for (int n = 0; n < 4; ++n) {
        int off = (((n * 16 + l15) * 128) + s * 64 + l4 * 16) ^ ((l15 & 7) << 4);
        bh[n] = *(const bf16x8*)(lb + off);
        bl[n] = *(const bf16x8*)(lb + 8192 + off);
      }
#pragma unroll
      for (int m = 0; m < 2; ++m) {
        bf16x8 aH = a[m * 4 + s * 2];
        bf16x8 aL = a[m * 4 + s * 2 + 1];
#pragma unroll
        for (int n = 0; n < 4; ++n) {
          acc[m][n] = __builtin_amdgcn_mfma_f32_16x16x32_bf16(aH, bh[n], acc[m][n], 0, 0, 0);
          acc[m][n] = __builtin_amdgcn_mfma_f32_16x16x32_bf16(aH, bl[n], acc[m][n], 0, 0, 0);
          acc[m][n] = __builtin_amdgcn_mfma_f32_16x16x32_bf16(aL, bh[n], acc[m][n], 0, 0, 0);
        }
      }
    }
  };

  int cb = 0;
  auto ITER = [&](bf16x8(&aC)[8], bf16x8(&aN)[8], int kt) {
    if (kt + 1 < NT) ALOAD(aN, kt + 1);
    if (kt + 2 < NT) {
      int sb = cb + 2; if (sb >= 3) sb -= 3;
      BSTAGE(sb, kt + 2);
    }
    __builtin_amdgcn_sched_barrier(0);
    if (kt + 2 < NT)      asm volatile("s_waitcnt vmcnt(16)" ::: "memory");
    else if (kt + 1 < NT) asm volatile("s_waitcnt vmcnt(12)" ::: "memory");
    else                  asm volatile("s_waitcnt vmcnt(0)" ::: "memory");
    __builtin_amdgcn_s_barrier();
    __builtin_amdgcn_sched_barrier(0);
    COMPUTE(cb, aC);
    __builtin_amdgcn_sched_barrier(0);
    __builtin_amdgcn_s_barrier();   // cb gets re-staged next iter (3-buf ring)
    __builtin_amdgcn_sched_barrier(0);
    if (++cb == 3) cb = 0;
  };

  ALOAD(a0, 0);
  BSTAGE(0, 0);
  BSTAGE(1, 1);
  for (int kt = 0; kt + 1 < NT; kt += 2) { ITER(a0, a1, kt); ITER(a1, a0, kt + 1); }
  if (NT & 1) ITER(a0, a1, NT - 1);

  // ---- lane-local epilogue: acc[m][n][j] = z[w*32+m*16+l4*4+j][gate n, col l15]
  const int jj = hc0 + l15;
  const float bi = C.bias[jj], bf_ = C.bias[1024 + jj];
  const float bg = C.bias[2048 + jj], bo = C.bias[3072 + jj];
  const int kk = jj & 63;
  const int s2 = (kk >> 5) & 1, c4 = (kk >> 3) & 3, e2 = kk & 7;
  char* hbase = C.hpk + (((size_t)(mb * 16 + (jj >> 6))) << 15) + e2 * 2;
#pragma unroll
  for (int m = 0; m < 2; ++m)
#pragma unroll
    for (int j = 0; j < 4; ++j) {
      const int r = w * 32 + m * 16 + l4 * 4 + j;   // row within 128-block
      const size_t gi = (size_t)(bm0 + r) * 1024 + jj;
      float zi = acc[m][0][j] + bi;
      float zf = acc[m][1][j] + bf_;
      float zg = acc[m][2][j] + bg;
      float zo = acc[m][3][j] + bo;
      float cp = C.cst[gi];
      float si = 1.f / (1.f + expf(-zi));
      float sf = 1.f / (1.f + expf(-zf));
      float so = 1.f / (1.f + expf(-zo));
      float cn = sf * cp + si * tanhf(zg);
      float hn = so * tanhf(cn);
      C.cst[gi] = cn;
      ushort hhi, hlo; split1(hn, hhi, hlo);
      const int mm = r >> 4;
      const int lane2 = (r & 15) | (c4 << 4);
      char* hb2 = hbase + ((mm * 4 + s2 * 2) * 64 + lane2) * 16;
      *(ushort*)hb2 = hhi;
      *(ushort*)(hb2 + 1024) = hlo;                 // lo slot (+64*16)
      if (C.outp) {                                  // fused projection
        float contrib = hn * C.Wout[jj];
        contrib += __shfl_xor(contrib, 1, 64);
        contrib += __shfl_xor(contrib, 2, 64);
        contrib += __shfl_xor(contrib, 4, 64);
        contrib += __shfl_xor(contrib, 8, 64);
        if (l15 == 0) atomicAdd(C.outp + bm0 + r, contrib);
      }
    }
}

// ---------------- diagonal tri-cell kernel ---------------------------------
template <bool ENC>
__global__ __launch_bounds__(256, 3) void tri_kernel(TriP P) {
  __shared__ __align__(16) char lds[3 * 16384];
  const int cell = blockIdx.x >> 8;
  if (!((P.active >> cell) & 1)) return;
  const int ib = blockIdx.x & 255;
  if (ENC && cell == 0) cell_dev<1>(lds, ib, P.c[0]);
  else                  cell_dev<16>(lds, ib, P.c[cell]);
}

extern "C" void kernel_launch(void* const* d_in, const int* in_sizes, int n_in,
                              void* d_out, int out_size, void* d_ws, size_t ws_size,
                              hipStream_t stream) {
  (void)in_sizes; (void)n_in; (void)ws_size;
  const float* x = (const float*)d_in[0];
  const float* Wih[6]; const float* Whh[6]; const float* bb[6];
  for (int i = 0; i < 6; ++i) {
    Wih[i] = (const float*)d_in[1 + 3 * i];
    Whh[i] = (const float*)d_in[2 + 3 * i];
    bb[i]  = (const float*)d_in[3 + 3 * i];
  }
  const float* Wout = (const float*)d_in[19];
  float* out = (float*)d_out;

  char* W = (char*)d_ws;
  const size_t MB2 = 2097152;
  float* c0 = (float*)(W + 0 * MB2);
  float* c1 = (float*)(W + 1 * MB2);
  float* c2 = (float*)(W + 2 * MB2);
  char* h0p[2] = { W + 3 * MB2, W + 4 * MB2 };
  char* h1p[2] = { W + 5 * MB2, W + 6 * MB2 };
  char* h2p[2] = { W + 7 * MB2, W + 8 * MB2 };
  char* yp = W + 9 * MB2;
  char* xp = W + 10 * MB2;                  // 168*4*32KB = 22,020,096 B
  char* wp[6];
  wp[0] = xp + 22020096;                    // 17*64*16KB = 17,825,792 B
  wp[1] = wp[0] + 17825792;                 // 32*64*16KB = 33,554,432 B each
  for (int i = 2; i < 6; ++i) wp[i] = wp[i - 1] + 33554432;

  hipMemsetAsync(W, 0, 9 * MB2, stream);                     // c + h state
  hipMemsetAsync(d_out, 0, (size_t)out_size * sizeof(float), stream);

  pack_w_kernel<<<dim3(1024), dim3(256), 0, stream>>>(
      Wih[0], Whh[0], (ushort*)wp[0], 64, 17, 64L * 17 * 2048);
  for (int i = 1; i < 6; ++i)
    pack_w_kernel<<<dim3(1024), dim3(256), 0, stream>>>(
        Wih[i], Whh[i], (ushort*)wp[i], 1024, 32, 64L * 32 * 2048);
  pack_x_frag<<<dim3(1024), dim3(256), 0, stream>>>(x, xp, 22020096L / 16);

  dim3 grid(768), block(256);

  // Encoder diagonals d=0..169: cell0 t=d (d<=167), cell1 t=d-1, cell2 t=d-2.
  // All reads from parity (d-1)&1, writes to parity d&1.
  for (int d = 0; d < 170; ++d) {
    const int rp = (d - 1) & 1, wpar = d & 1;
    TriP P{};
    P.active = (d <= 167 ? 1u : 0u) | (d >= 1 && d <= 168 ? 2u : 0u)
             | (d >= 2 ? 4u : 0u);
    P.c[0] = { xp + (size_t)d * 131072, h0p[rp], wp[0], bb[0], c0,
               h0p[wpar], nullptr, nullptr };
    P.c[1] = { h0p[rp], h1p[rp], wp[1], bb[1], c1, h1p[wpar], nullptr, nullptr };
    P.c[2] = { h1p[rp], h2p[rp], wp[2], bb[2], c2, h2p[wpar], nullptr, nullptr };
    tri_kernel<true><<<grid, block, 0, stream>>>(P);
  }

  // y = encoder-final h2 (written at d=169 -> parity 1)
  hipMemcpyAsync(yp, h2p[1], MB2, hipMemcpyDeviceToDevice, stream);

  // Decoder diagonals D=170..195: cell0 (df) D<=193, cell1 171..194,
  // cell2 172..195 (fused projection, t = D-172).
  for (int D = 170; D < 196; ++D) {
    const int rp = (D - 1) & 1, wpar = D & 1;
    TriP P{};
    P.active = (D <= 193 ? 1u : 0u) | (D >= 171 && D <= 194 ? 2u : 0u)
             | (D >= 172 ? 4u : 0u);
    P.c[0] = { yp, h0p[rp], wp[3], bb[3], c0, h0p[wpar], nullptr, nullptr };
    P.c[1] = { h0p[rp], h1p[rp], wp[4], bb[4], c1, h1p[wpar], nullptr, nullptr };
    P.c[2] = { h1p[rp], h2p[rp], wp[5], bb[5], c2, h2p[wpar],
               out + (size_t)(D - 172) * 512, Wout };
    tri_kernel<false><<<grid, block, 0, stream>>>(P);
  }
}